// Round 2
// baseline (3424.759 us; speedup 1.0000x reference)
//
#include <hip/hip_runtime.h>
#include <hip/hip_fp16.h>
#include <math.h>
#include <stdio.h>

// N=50000 nodes, E=800000 edges, IN=128, C=64, H=8, H*C=512
// Intermediates stored fp16 (fp32 math) to keep workspace ~260 MB.

// ---------------- CSR build ----------------
__global__ void zero_int_kernel(int* p, int n) {
  int i = blockIdx.x * blockDim.x + threadIdx.x;
  if (i < n) p[i] = 0;
}

__global__ void degree_kernel(const int* __restrict__ dst, int* __restrict__ deg, int E) {
  int e = blockIdx.x * blockDim.x + threadIdx.x;
  if (e < E) atomicAdd(&deg[dst[e]], 1);
}

// single block, 1024 threads: chunk-per-thread sums + Hillis-Steele LDS scan
__global__ __launch_bounds__(1024)
void exscan_kernel(const int* __restrict__ deg, int* __restrict__ rowptr,
                   int* __restrict__ cursor, int n) {
  __shared__ int tmp[1024];
  int tid = threadIdx.x;
  int chunk = (n + 1023) / 1024;
  int lo = tid * chunk;
  int hi = min(n, lo + chunk);
  int s = 0;
  for (int i = lo; i < hi; ++i) s += deg[i];
  int mysum = s;
  tmp[tid] = s;
  __syncthreads();
  for (int off = 1; off < 1024; off <<= 1) {
    int v = (tid >= off) ? tmp[tid - off] : 0;
    __syncthreads();
    tmp[tid] += v;
    __syncthreads();
  }
  int run = tmp[tid] - mysum;  // exclusive prefix of this chunk
  if (tid == 0) { rowptr[0] = 0; cursor[0] = 0; }
  for (int i = lo; i < hi; ++i) {
    run += deg[i];
    rowptr[i + 1] = run;
    cursor[i + 1] = run;
  }
}

__global__ void scatter_kernel(const int* __restrict__ src, const int* __restrict__ dst,
                               int* __restrict__ cursor, int* __restrict__ col, int E) {
  int e = blockIdx.x * blockDim.x + threadIdx.x;
  if (e < E) {
    int pos = atomicAdd(&cursor[dst[e]], 1);
    col[pos] = src[e];
  }
}

// ---------------- fused QKVS GEMM: O_m = X @ W_m + b_m, m in {q,k,v,s} ----------------
// 64x64 tile, 256 threads, 4x4 accum per thread. fp32 math, fp16 output.
template <typename IT>
__global__ __launch_bounds__(256)
void gemm4_kernel(const IT* __restrict__ X,
                  const float* __restrict__ Wq, const float* __restrict__ Wk,
                  const float* __restrict__ Wv, const float* __restrict__ Ws,
                  const float* __restrict__ bq, const float* __restrict__ bk,
                  const float* __restrict__ bv, const float* __restrict__ bs,
                  __half* __restrict__ Oq, __half* __restrict__ Ok,
                  __half* __restrict__ Ov, __half* __restrict__ Os,
                  int N, int Din, int Dout) {
  int tilesPerMat = Dout >> 6;
  int mat = blockIdx.y / tilesPerMat;
  int cb = blockIdx.y % tilesPerMat;
  const float* W = (mat == 0) ? Wq : (mat == 1) ? Wk : (mat == 2) ? Wv : Ws;
  const float* bias = (mat == 0) ? bq : (mat == 1) ? bk : (mat == 2) ? bv : bs;
  __half* O = (mat == 0) ? Oq : (mat == 1) ? Ok : (mat == 2) ? Ov : Os;

  int m0 = blockIdx.x * 64;
  int c0 = cb * 64;

  __shared__ float As[64][33];
  __shared__ float Bs[32][64];

  int tid = threadIdx.x;
  int tx = tid & 15;
  int ty = tid >> 4;

  float acc[4][4] = {};

  for (int k0 = 0; k0 < Din; k0 += 32) {
    // A tile: 64 rows x 32 k
    if constexpr (sizeof(IT) == 4) {
#pragma unroll
      for (int l = 0; l < 2; ++l) {
        int idx = tid + l * 256;
        int row = idx >> 3;
        int kc = (idx & 7) << 2;
        int grow = m0 + row;
        float4 v = make_float4(0.f, 0.f, 0.f, 0.f);
        if (grow < N) v = *(const float4*)((const float*)X + (size_t)grow * Din + k0 + kc);
        As[row][kc] = v.x; As[row][kc + 1] = v.y; As[row][kc + 2] = v.z; As[row][kc + 3] = v.w;
      }
    } else {
      int row = tid >> 2;
      int kc = (tid & 3) << 3;  // 8 halves = 16B
      int grow = m0 + row;
      float4 raw = make_float4(0.f, 0.f, 0.f, 0.f);
      if (grow < N) raw = *(const float4*)((const __half*)X + (size_t)grow * Din + k0 + kc);
      const __half2* hp = (const __half2*)&raw;
#pragma unroll
      for (int j = 0; j < 4; ++j) {
        float2 f = __half22float2(hp[j]);
        As[row][kc + 2 * j] = f.x;
        As[row][kc + 2 * j + 1] = f.y;
      }
    }
    // B tile: 32 k x 64 cols (fp32 weights)
#pragma unroll
    for (int l = 0; l < 2; ++l) {
      int idx = tid + l * 256;
      int kr = idx >> 4;
      int cc = (idx & 15) << 2;
      float4 v = *(const float4*)(W + (size_t)(k0 + kr) * Dout + c0 + cc);
      *(float4*)&Bs[kr][cc] = v;
    }
    __syncthreads();
#pragma unroll
    for (int kk = 0; kk < 32; ++kk) {
      float a0 = As[ty * 4 + 0][kk];
      float a1 = As[ty * 4 + 1][kk];
      float a2 = As[ty * 4 + 2][kk];
      float a3 = As[ty * 4 + 3][kk];
      float4 b = *(float4*)&Bs[kk][tx * 4];
      acc[0][0] += a0 * b.x; acc[0][1] += a0 * b.y; acc[0][2] += a0 * b.z; acc[0][3] += a0 * b.w;
      acc[1][0] += a1 * b.x; acc[1][1] += a1 * b.y; acc[1][2] += a1 * b.z; acc[1][3] += a1 * b.w;
      acc[2][0] += a2 * b.x; acc[2][1] += a2 * b.y; acc[2][2] += a2 * b.z; acc[2][3] += a2 * b.w;
      acc[3][0] += a3 * b.x; acc[3][1] += a3 * b.y; acc[3][2] += a3 * b.z; acc[3][3] += a3 * b.w;
    }
    __syncthreads();
  }

  float4 bb = *(const float4*)(bias + c0 + tx * 4);
#pragma unroll
  for (int i = 0; i < 4; ++i) {
    int grow = m0 + ty * 4 + i;
    if (grow < N) {
      __half2 p0 = __floats2half2_rn(acc[i][0] + bb.x, acc[i][1] + bb.y);
      __half2 p1 = __floats2half2_rn(acc[i][2] + bb.z, acc[i][3] + bb.w);
      __half2* dst = (__half2*)(O + (size_t)grow * Dout + c0 + tx * 4);
      dst[0] = p0;
      dst[1] = p1;
    }
  }
}

// ---------------- attention, H=8 C=64: one node per block, one wave per head ----------------
// Writes h = relu(attn + S) IN PLACE into out (each thread touches only its own element;
// out may alias S).
__global__ __launch_bounds__(512)
void attn_h8_kernel(const __half* __restrict__ Q, const __half* __restrict__ K,
                    const __half* __restrict__ V, const __half* __restrict__ S,
                    const int* __restrict__ rowptr, const int* __restrict__ col,
                    __half* __restrict__ out) {
  int n = blockIdx.x;
  int tid = threadIdx.x;  // head*64 + c
  size_t base = (size_t)n * 512 + tid;
  float q = __half2float(Q[base]);
  int e0 = rowptr[n], e1 = rowptr[n + 1];
  float m = -INFINITY, l = 0.f, o = 0.f;
  for (int i = e0; i < e1; ++i) {
    int s = col[i];
    float kv = __half2float(K[(size_t)s * 512 + tid]);
    float vv = __half2float(V[(size_t)s * 512 + tid]);
    float p = q * kv;
#pragma unroll
    for (int off = 32; off > 0; off >>= 1) p += __shfl_xor(p, off, 64);
    float a = p * 0.125f;  // 1/sqrt(64)
    float mn = fmaxf(m, a);
    float sc = __expf(m - mn);  // exp(-inf)=0 on first edge
    float e = __expf(a - mn);
    l = l * sc + e;
    o = o * sc + e * vv;
    m = mn;
  }
  float r = o / (l + 1e-16f) + __half2float(S[base]);
  r = fmaxf(r, 0.f);  // relu (layers 0/1 only use this kernel)
  out[base] = __float2half(r);
}

// ---------------- attention, H=1 C=64: 4 nodes per block, wave per node; fp32 out ----------------
__global__ __launch_bounds__(256)
void attn_h1_kernel(const __half* __restrict__ Q, const __half* __restrict__ K,
                    const __half* __restrict__ V, const __half* __restrict__ S,
                    const int* __restrict__ rowptr, const int* __restrict__ col,
                    float* __restrict__ out, int N) {
  int n = blockIdx.x * 4 + (threadIdx.x >> 6);
  if (n >= N) return;
  int lane = threadIdx.x & 63;
  size_t base = (size_t)n * 64 + lane;
  float q = __half2float(Q[base]);
  int e0 = rowptr[n], e1 = rowptr[n + 1];
  float m = -INFINITY, l = 0.f, o = 0.f;
  for (int i = e0; i < e1; ++i) {
    int s = col[i];
    float kv = __half2float(K[(size_t)s * 64 + lane]);
    float vv = __half2float(V[(size_t)s * 64 + lane]);
    float p = q * kv;
#pragma unroll
    for (int off = 32; off > 0; off >>= 1) p += __shfl_xor(p, off, 64);
    float a = p * 0.125f;
    float mn = fmaxf(m, a);
    float sc = __expf(m - mn);
    float e = __expf(a - mn);
    l = l * sc + e;
    o = o * sc + e * vv;
    m = mn;
  }
  out[base] = o / (l + 1e-16f) + __half2float(S[base]);
}

extern "C" void kernel_launch(void* const* d_in, const int* in_sizes, int n_in,
                              void* d_out, int out_size, void* d_ws, size_t ws_size,
                              hipStream_t stream) {
  const float* x = (const float*)d_in[0];
  const int* ei = (const int*)d_in[1];
  const int N = in_sizes[0] / 128;
  const int E = in_sizes[1] / 2;
  const int* srcp = ei;
  const int* dstp = ei + E;

  const float* Wq0 = (const float*)d_in[2];  const float* bq0 = (const float*)d_in[3];
  const float* Wk0 = (const float*)d_in[4];  const float* bk0 = (const float*)d_in[5];
  const float* Wv0 = (const float*)d_in[6];  const float* bv0 = (const float*)d_in[7];
  const float* Ws0 = (const float*)d_in[8];  const float* bs0 = (const float*)d_in[9];
  const float* Wq1 = (const float*)d_in[10]; const float* bq1 = (const float*)d_in[11];
  const float* Wk1 = (const float*)d_in[12]; const float* bk1 = (const float*)d_in[13];
  const float* Wv1 = (const float*)d_in[14]; const float* bv1 = (const float*)d_in[15];
  const float* Ws1 = (const float*)d_in[16]; const float* bs1 = (const float*)d_in[17];
  const float* Wq2 = (const float*)d_in[18]; const float* bq2 = (const float*)d_in[19];
  const float* Wk2 = (const float*)d_in[20]; const float* bk2 = (const float*)d_in[21];
  const float* Wv2 = (const float*)d_in[22]; const float* bv2 = (const float*)d_in[23];
  const float* Ws2 = (const float*)d_in[24]; const float* bs2 = (const float*)d_in[25];

  // workspace: 5 fp16 [N,512] buffers + CSR ints
  const size_t NM = (size_t)N * 512;
  __half* Abuf = (__half*)d_ws;   // Q (l0/l1), then l2's 4 small outputs carved here
  __half* Bbuf = Abuf + NM;       // K
  __half* Cbuf = Bbuf + NM;       // V
  __half* Dbuf = Cbuf + NM;       // S0 -> h0 (in place)
  __half* Ebuf = Dbuf + NM;       // S1 -> h1 (in place)
  int* deg = (int*)(Ebuf + NM);
  int* rowptr = deg + N;
  int* cursor = rowptr + N + 1;
  int* colv = cursor + N + 1;

  size_t need = (char*)(colv + E) - (char*)d_ws;
  if (ws_size < need) {
    fprintf(stderr, "kernel_launch: ws_size=%zu < need=%zu — aborting cleanly\n",
            ws_size, need);
    return;
  }

  // ---- CSR build ----
  zero_int_kernel<<<(N + 255) / 256, 256, 0, stream>>>(deg, N);
  degree_kernel<<<(E + 255) / 256, 256, 0, stream>>>(dstp, deg, E);
  exscan_kernel<<<1, 1024, 0, stream>>>(deg, rowptr, cursor, N);
  scatter_kernel<<<(E + 255) / 256, 256, 0, stream>>>(srcp, dstp, cursor, colv, E);

  const int mtiles = (N + 63) / 64;

  // ---- layer 0: 128 -> 512 (fp32 input x) ----
  gemm4_kernel<float><<<dim3(mtiles, 4 * (512 / 64)), 256, 0, stream>>>(
      x, Wq0, Wk0, Wv0, Ws0, bq0, bk0, bv0, bs0, Abuf, Bbuf, Cbuf, Dbuf, N, 128, 512);
  attn_h8_kernel<<<N, 512, 0, stream>>>(Abuf, Bbuf, Cbuf, Dbuf, rowptr, colv, Dbuf);

  // ---- layer 1: 512 -> 512 (fp16 input h0=Dbuf) ----
  gemm4_kernel<__half><<<dim3(mtiles, 4 * (512 / 64)), 256, 0, stream>>>(
      Dbuf, Wq1, Wk1, Wv1, Ws1, bq1, bk1, bv1, bs1, Abuf, Bbuf, Cbuf, Ebuf, N, 512, 512);
  attn_h8_kernel<<<N, 512, 0, stream>>>(Abuf, Bbuf, Cbuf, Ebuf, rowptr, colv, Ebuf);

  // ---- layer 2: 512 -> 64, heads=1, no relu (fp16 input h1=Ebuf) ----
  __half* Q2 = Abuf;
  __half* K2 = Abuf + (size_t)N * 64;
  __half* V2 = Abuf + (size_t)2 * N * 64;
  __half* S2 = Abuf + (size_t)3 * N * 64;
  gemm4_kernel<__half><<<dim3(mtiles, 4 * (64 / 64)), 256, 0, stream>>>(
      Ebuf, Wq2, Wk2, Wv2, Ws2, bq2, bk2, bv2, bs2, Q2, K2, V2, S2, N, 512, 64);
  attn_h1_kernel<<<(N + 3) / 4, 256, 0, stream>>>(Q2, K2, V2, S2, rowptr, colv,
                                                  (float*)d_out, N);
}

// Round 3
// 1794.289 us; speedup vs baseline: 1.9087x; 1.9087x over previous
//
#include <hip/hip_runtime.h>
#include <hip/hip_fp16.h>
#include <math.h>
#include <stdio.h>

// N=50000, E=800000, IN=128, C=64, H=8, H*C=512
// Round 3: fp16-MFMA fused GEMM (m97-style: 128x128 tile, global_load_lds,
// 16x16x32 f16 MFMA). Intermediates fp16; all math fp32.
// ws budget ~262 MB (must stay under ~268 MB = 256 MiB).

using f16x8 = __attribute__((ext_vector_type(8))) _Float16;
using f32x4 = __attribute__((ext_vector_type(4))) float;

__device__ __forceinline__ void load_lds16(const void* g, void* l) {
  __builtin_amdgcn_global_load_lds((const __attribute__((address_space(1))) void*)g,
                                   (__attribute__((address_space(3))) void*)l,
                                   16, 0, 0);
}

// ---------------- CSR build ----------------
__global__ void zero_int_kernel(int* p, int n) {
  int i = blockIdx.x * blockDim.x + threadIdx.x;
  if (i < n) p[i] = 0;
}

__global__ void degree_kernel(const int* __restrict__ dst, int* __restrict__ deg, int E) {
  int e = blockIdx.x * blockDim.x + threadIdx.x;
  if (e < E) atomicAdd(&deg[dst[e]], 1);
}

__global__ __launch_bounds__(1024)
void exscan_kernel(const int* __restrict__ deg, int* __restrict__ rowptr,
                   int* __restrict__ cursor, int n) {
  __shared__ int tmp[1024];
  int tid = threadIdx.x;
  int chunk = (n + 1023) / 1024;
  int lo = tid * chunk;
  int hi = min(n, lo + chunk);
  int s = 0;
  for (int i = lo; i < hi; ++i) s += deg[i];
  int mysum = s;
  tmp[tid] = s;
  __syncthreads();
  for (int off = 1; off < 1024; off <<= 1) {
    int v = (tid >= off) ? tmp[tid - off] : 0;
    __syncthreads();
    tmp[tid] += v;
    __syncthreads();
  }
  int run = tmp[tid] - mysum;
  if (tid == 0) { rowptr[0] = 0; cursor[0] = 0; }
  for (int i = lo; i < hi; ++i) {
    run += deg[i];
    rowptr[i + 1] = run;
    cursor[i + 1] = run;
  }
}

__global__ void scatter_kernel(const int* __restrict__ src, const int* __restrict__ dst,
                               int* __restrict__ cursor, int* __restrict__ col, int E) {
  int e = blockIdx.x * blockDim.x + threadIdx.x;
  if (e < E) {
    int pos = atomicAdd(&cursor[dst[e]], 1);
    col[pos] = src[e];
  }
}

// ---------------- prep kernels ----------------
__global__ void convert_x_kernel(const float* __restrict__ x, __half* __restrict__ X16,
                                 int N, int Npad) {
  int i = blockIdx.x * 256 + threadIdx.x;
  if (i < Npad * 128) {
    int row = i >> 7;
    X16[i] = __float2half((row < N) ? x[i] : 0.f);
  }
}

__global__ void zero_pad_kernel(__half* __restrict__ H, int startElem, int numElem) {
  int i = blockIdx.x * 256 + threadIdx.x;
  if (i < numElem) H[startElem + i] = __float2half(0.f);
}

// transpose+cast: W_m fp32 [K x D] -> Wt fp16 rows [4D x K], Wt[m*D+c][k] = W_m[k][c]
__global__ __launch_bounds__(256)
void transpose4_kernel(const float* __restrict__ W0, const float* __restrict__ W1,
                       const float* __restrict__ W2, const float* __restrict__ W3,
                       __half* __restrict__ Wt, int K, int D) {
  const float* W = (blockIdx.z == 0) ? W0 : (blockIdx.z == 1) ? W1
                 : (blockIdx.z == 2) ? W2 : W3;
  __shared__ float t[32][33];
  int c0 = blockIdx.x * 32, k0 = blockIdx.y * 32;
  int tx = threadIdx.x, ty = threadIdx.y;  // (32,8)
#pragma unroll
  for (int r = 0; r < 4; ++r)
    t[ty + 8 * r][tx] = W[(size_t)(k0 + ty + 8 * r) * D + c0 + tx];
  __syncthreads();
#pragma unroll
  for (int r = 0; r < 4; ++r)
    Wt[(size_t)(blockIdx.z * D + c0 + ty + 8 * r) * K + k0 + tx] =
        __float2half(t[tx][ty + 8 * r]);
}

__global__ void bias4_kernel(const float* __restrict__ b0, const float* __restrict__ b1,
                             const float* __restrict__ b2, const float* __restrict__ b3,
                             float* __restrict__ bias_all, int D) {
  int c = blockIdx.x * 256 + threadIdx.x;
  if (c < 4 * D) {
    int m = c / D;
    const float* b = (m == 0) ? b0 : (m == 1) ? b1 : (m == 2) ? b2 : b3;
    bias_all[c] = b[c - m * D];
  }
}

// ---------------- MFMA GEMM: O[M x Ntot] = A[M x K] @ Wt^T + bias ----------------
// A fp16 row-major (lda), Wt fp16 [Ntot x K] (rows = output cols), O fp16.
// 128x128 tile, 256 thr = 4 waves (2x2 of 64x64), BK=32, 16x16x32 f16 MFMA.
// M must be a multiple of 128 (padded buffers); Ntot multiple of 128.
__global__ __launch_bounds__(256)
void gemm_mfma_kernel(const __half* __restrict__ A, int lda,
                      const __half* __restrict__ Wt,
                      const float* __restrict__ bias,
                      __half* __restrict__ O, int Ntot, int K) {
  __shared__ __align__(16) __half As[128 * 32];
  __shared__ __align__(16) __half Bs[128 * 32];
  int tid = threadIdx.x;
  int wave = tid >> 6, lane = tid & 63;
  int wr = wave >> 1, wc = wave & 1;
  int m0 = blockIdx.x * 128;
  int n0 = blockIdx.y * 128;
  int lr = lane >> 2;          // row within 16-row chunk
  int lk = (lane & 3) * 8;     // k offset (halves)
  int quad = lane >> 4, rr = lane & 15;

  f32x4 acc[4][4] = {};

  for (int kt = 0; kt < K; kt += 32) {
#pragma unroll
    for (int p = 0; p < 2; ++p) {
      int chunk = p * 64 + wave * 16;  // wave-uniform
      const __half* ga = A + (size_t)(m0 + chunk + lr) * lda + kt + lk;
      load_lds16(ga, &As[chunk * 32]);
      const __half* gb = Wt + (size_t)(n0 + chunk + lr) * K + kt + lk;
      load_lds16(gb, &Bs[chunk * 32]);
    }
    __syncthreads();  // drains vmcnt for global_load_lds
    f16x8 a[4], b[4];
#pragma unroll
    for (int i = 0; i < 4; ++i)
      a[i] = *(const f16x8*)&As[(wr * 64 + i * 16 + rr) * 32 + quad * 8];
#pragma unroll
    for (int j = 0; j < 4; ++j)
      b[j] = *(const f16x8*)&Bs[(wc * 64 + j * 16 + rr) * 32 + quad * 8];
#pragma unroll
    for (int i = 0; i < 4; ++i)
#pragma unroll
      for (int j = 0; j < 4; ++j)
        acc[i][j] = __builtin_amdgcn_mfma_f32_16x16x32_f16(a[i], b[j], acc[i][j], 0, 0, 0);
    __syncthreads();
  }

  // C/D layout: col = lane&15, row = (lane>>4)*4 + reg
  int col = lane & 15, rb = (lane >> 4) * 4;
  float bj[4];
#pragma unroll
  for (int j = 0; j < 4; ++j) bj[j] = bias[n0 + wc * 64 + j * 16 + col];
#pragma unroll
  for (int i = 0; i < 4; ++i) {
#pragma unroll
    for (int j = 0; j < 4; ++j) {
      int gc = n0 + wc * 64 + j * 16 + col;
#pragma unroll
      for (int r = 0; r < 4; ++r) {
        int gr = m0 + wr * 64 + i * 16 + rb + r;
        O[(size_t)gr * Ntot + gc] = __float2half(acc[i][j][r] + bj[j]);
      }
    }
  }
}

// ---------------- attention H=8 C=64: one node/block, one wave/head ----------------
// QKVS = O_all row stride 2048; writes relu(attn + S) into compact H [n*512+tid].
__global__ __launch_bounds__(512)
void attn_h8_kernel(const __half* __restrict__ QKVS,
                    const int* __restrict__ rowptr, const int* __restrict__ col,
                    __half* __restrict__ Hout) {
  int n = blockIdx.x;
  int tid = threadIdx.x;  // head*64 + c
  size_t rbase = (size_t)n * 2048;
  float q = __half2float(QKVS[rbase + tid]);
  int e0 = rowptr[n], e1 = rowptr[n + 1];
  float m = -INFINITY, l = 0.f, o = 0.f;
  for (int i = e0; i < e1; ++i) {
    int s = col[i];
    size_t sb = (size_t)s * 2048;
    float kv = __half2float(QKVS[sb + 512 + tid]);
    float vv = __half2float(QKVS[sb + 1024 + tid]);
    float p = q * kv;
#pragma unroll
    for (int off = 32; off > 0; off >>= 1) p += __shfl_xor(p, off, 64);
    float a = p * 0.125f;  // 1/sqrt(64)
    float mn = fmaxf(m, a);
    float sc = __expf(m - mn);
    float e = __expf(a - mn);
    l = l * sc + e;
    o = o * sc + e * vv;
    m = mn;
  }
  float r = o / (l + 1e-16f) + __half2float(QKVS[rbase + 1536 + tid]);
  Hout[(size_t)n * 512 + tid] = __float2half(fmaxf(r, 0.f));
}

// ---------------- attention H=1 C=64: 4 nodes/block, wave/node; fp32 out ----------------
__global__ __launch_bounds__(256)
void attn_h1_kernel(const __half* __restrict__ QKVS,
                    const int* __restrict__ rowptr, const int* __restrict__ col,
                    float* __restrict__ out, int N) {
  int n = blockIdx.x * 4 + (threadIdx.x >> 6);
  if (n >= N) return;
  int lane = threadIdx.x & 63;
  size_t rbase = (size_t)n * 256;
  float q = __half2float(QKVS[rbase + lane]);
  int e0 = rowptr[n], e1 = rowptr[n + 1];
  float m = -INFINITY, l = 0.f, o = 0.f;
  for (int i = e0; i < e1; ++i) {
    int s = col[i];
    size_t sb = (size_t)s * 256;
    float kv = __half2float(QKVS[sb + 64 + lane]);
    float vv = __half2float(QKVS[sb + 128 + lane]);
    float p = q * kv;
#pragma unroll
    for (int off = 32; off > 0; off >>= 1) p += __shfl_xor(p, off, 64);
    float a = p * 0.125f;
    float mn = fmaxf(m, a);
    float sc = __expf(m - mn);
    float e = __expf(a - mn);
    l = l * sc + e;
    o = o * sc + e * vv;
    m = mn;
  }
  out[(size_t)n * 64 + lane] = o / (l + 1e-16f) + __half2float(QKVS[rbase + 192 + lane]);
}

extern "C" void kernel_launch(void* const* d_in, const int* in_sizes, int n_in,
                              void* d_out, int out_size, void* d_ws, size_t ws_size,
                              hipStream_t stream) {
  const float* x = (const float*)d_in[0];
  const int* ei = (const int*)d_in[1];
  const int N = in_sizes[0] / 128;
  const int E = in_sizes[1] / 2;
  const int Npad = ((N + 127) / 128) * 128;
  const int* srcp = ei;
  const int* dstp = ei + E;

  const float* Wq0 = (const float*)d_in[2];  const float* bq0 = (const float*)d_in[3];
  const float* Wk0 = (const float*)d_in[4];  const float* bk0 = (const float*)d_in[5];
  const float* Wv0 = (const float*)d_in[6];  const float* bv0 = (const float*)d_in[7];
  const float* Ws0 = (const float*)d_in[8];  const float* bs0 = (const float*)d_in[9];
  const float* Wq1 = (const float*)d_in[10]; const float* bq1 = (const float*)d_in[11];
  const float* Wk1 = (const float*)d_in[12]; const float* bk1 = (const float*)d_in[13];
  const float* Wv1 = (const float*)d_in[14]; const float* bv1 = (const float*)d_in[15];
  const float* Ws1 = (const float*)d_in[16]; const float* bs1 = (const float*)d_in[17];
  const float* Wq2 = (const float*)d_in[18]; const float* bq2 = (const float*)d_in[19];
  const float* Wk2 = (const float*)d_in[20]; const float* bk2 = (const float*)d_in[21];
  const float* Wv2 = (const float*)d_in[22]; const float* bv2 = (const float*)d_in[23];
  const float* Ws2 = (const float*)d_in[24]; const float* bs2 = (const float*)d_in[25];

  // ---- workspace layout (~262.2 MB) ----
  char* p = (char*)d_ws;
  __half* O_all = (__half*)p;            p += (size_t)Npad * 2048 * 2;  // 205.0 MB
  __half* H     = (__half*)p;            p += (size_t)Npad * 512 * 2;   // 51.25 MB
  __half* X16   = H;  // aliases head of H; dead before H is first written
  __half* Wt    = (__half*)p;            p += (size_t)2048 * 512 * 2;   // 2 MB
  float* bias_all = (float*)p;           p += 2048 * 4;                 // 8 KB
  int* deg    = (int*)p;                 p += (size_t)N * 4;
  int* rowptr = (int*)p;                 p += (size_t)(N + 1) * 4;
  int* cursor = (int*)p;                 p += (size_t)(N + 1) * 4;
  int* colv   = (int*)p;                 p += (size_t)E * 4;
  size_t need = p - (char*)d_ws;
  if (ws_size < need) {
    fprintf(stderr, "kernel_launch: ws_size=%zu < need=%zu — aborting cleanly\n",
            ws_size, need);
    return;
  }

  // ---- prep: x -> fp16 (zero pad rows), zero H pad rows ----
  convert_x_kernel<<<(Npad * 128 + 255) / 256, 256, 0, stream>>>(x, X16, N, Npad);
  zero_pad_kernel<<<((Npad - N) * 512 + 255) / 256, 256, 0, stream>>>(
      H, N * 512, (Npad - N) * 512);

  // ---- CSR build ----
  zero_int_kernel<<<(N + 255) / 256, 256, 0, stream>>>(deg, N);
  degree_kernel<<<(E + 255) / 256, 256, 0, stream>>>(dstp, deg, E);
  exscan_kernel<<<1, 1024, 0, stream>>>(deg, rowptr, cursor, N);
  scatter_kernel<<<(E + 255) / 256, 256, 0, stream>>>(srcp, dstp, cursor, colv, E);

  const int mtiles = Npad / 128;

  // ---- layer 0: K=128 -> Ntot=2048 ----
  transpose4_kernel<<<dim3(512 / 32, 128 / 32, 4), dim3(32, 8), 0, stream>>>(
      Wq0, Wk0, Wv0, Ws0, Wt, 128, 512);
  bias4_kernel<<<(2048 + 255) / 256, 256, 0, stream>>>(bq0, bk0, bv0, bs0, bias_all, 512);
  gemm_mfma_kernel<<<dim3(mtiles, 2048 / 128), 256, 0, stream>>>(
      X16, 128, Wt, bias_all, O_all, 2048, 128);
  attn_h8_kernel<<<N, 512, 0, stream>>>(O_all, rowptr, colv, H);

  // ---- layer 1: K=512 -> Ntot=2048 ----
  transpose4_kernel<<<dim3(512 / 32, 512 / 32, 4), dim3(32, 8), 0, stream>>>(
      Wq1, Wk1, Wv1, Ws1, Wt, 512, 512);
  bias4_kernel<<<(2048 + 255) / 256, 256, 0, stream>>>(bq1, bk1, bv1, bs1, bias_all, 512);
  gemm_mfma_kernel<<<dim3(mtiles, 2048 / 128), 256, 0, stream>>>(
      H, 512, Wt, bias_all, O_all, 2048, 512);
  attn_h8_kernel<<<N, 512, 0, stream>>>(O_all, rowptr, colv, H);

  // ---- layer 2: K=512 -> Ntot=256 (4 x 64) ----
  transpose4_kernel<<<dim3(64 / 32, 512 / 32, 4), dim3(32, 8), 0, stream>>>(
      Wq2, Wk2, Wv2, Ws2, Wt, 512, 64);
  bias4_kernel<<<1, 256, 0, stream>>>(bq2, bk2, bv2, bs2, bias_all, 64);
  gemm_mfma_kernel<<<dim3(mtiles, 256 / 128), 256, 0, stream>>>(
      H, 512, Wt, bias_all, O_all, 256, 512);
  attn_h1_kernel<<<(N + 3) / 4, 256, 0, stream>>>(O_all, rowptr, colv, (float*)d_out, N);
}

// Round 4
// 1113.088 us; speedup vs baseline: 3.0768x; 1.6120x over previous
//
#include <hip/hip_runtime.h>
#include <hip/hip_fp16.h>
#include <math.h>
#include <stdio.h>

// N=50000, E=800000, IN=128, C=64, H=8, H*C=512
// Round 4: attention restructured — one wave per node (lane owns 8 channels),
// 16B/lane K/V gathers, 3-shuffle head reduction, NT hints for streamed Q/S/H.
// GEMM unchanged (m97-style fp16 MFMA).

using f16x8 = __attribute__((ext_vector_type(8))) _Float16;
using f32x4 = __attribute__((ext_vector_type(4))) float;

__device__ __forceinline__ void load_lds16(const void* g, void* l) {
  __builtin_amdgcn_global_load_lds((const __attribute__((address_space(1))) void*)g,
                                   (__attribute__((address_space(3))) void*)l,
                                   16, 0, 0);
}

// ---------------- CSR build ----------------
__global__ void zero_int_kernel(int* p, int n) {
  int i = blockIdx.x * blockDim.x + threadIdx.x;
  if (i < n) p[i] = 0;
}

__global__ void degree_kernel(const int* __restrict__ dst, int* __restrict__ deg, int E) {
  int e = blockIdx.x * blockDim.x + threadIdx.x;
  if (e < E) atomicAdd(&deg[dst[e]], 1);
}

__global__ __launch_bounds__(1024)
void exscan_kernel(const int* __restrict__ deg, int* __restrict__ rowptr,
                   int* __restrict__ cursor, int n) {
  __shared__ int tmp[1024];
  int tid = threadIdx.x;
  int chunk = (n + 1023) / 1024;
  int lo = tid * chunk;
  int hi = min(n, lo + chunk);
  int s = 0;
  for (int i = lo; i < hi; ++i) s += deg[i];
  int mysum = s;
  tmp[tid] = s;
  __syncthreads();
  for (int off = 1; off < 1024; off <<= 1) {
    int v = (tid >= off) ? tmp[tid - off] : 0;
    __syncthreads();
    tmp[tid] += v;
    __syncthreads();
  }
  int run = tmp[tid] - mysum;
  if (tid == 0) { rowptr[0] = 0; cursor[0] = 0; }
  for (int i = lo; i < hi; ++i) {
    run += deg[i];
    rowptr[i + 1] = run;
    cursor[i + 1] = run;
  }
}

__global__ void scatter_kernel(const int* __restrict__ src, const int* __restrict__ dst,
                               int* __restrict__ cursor, int* __restrict__ col, int E) {
  int e = blockIdx.x * blockDim.x + threadIdx.x;
  if (e < E) {
    int pos = atomicAdd(&cursor[dst[e]], 1);
    col[pos] = src[e];
  }
}

// ---------------- prep kernels ----------------
__global__ void convert_x_kernel(const float* __restrict__ x, __half* __restrict__ X16,
                                 int N, int Npad) {
  int i = blockIdx.x * 256 + threadIdx.x;
  if (i < Npad * 128) {
    int row = i >> 7;
    X16[i] = __float2half((row < N) ? x[i] : 0.f);
  }
}

__global__ void zero_pad_kernel(__half* __restrict__ H, int startElem, int numElem) {
  int i = blockIdx.x * 256 + threadIdx.x;
  if (i < numElem) H[startElem + i] = __float2half(0.f);
}

// transpose+cast: W_m fp32 [K x D] -> Wt fp16 rows [4D x K], Wt[m*D+c][k] = W_m[k][c]
__global__ __launch_bounds__(256)
void transpose4_kernel(const float* __restrict__ W0, const float* __restrict__ W1,
                       const float* __restrict__ W2, const float* __restrict__ W3,
                       __half* __restrict__ Wt, int K, int D) {
  const float* W = (blockIdx.z == 0) ? W0 : (blockIdx.z == 1) ? W1
                 : (blockIdx.z == 2) ? W2 : W3;
  __shared__ float t[32][33];
  int c0 = blockIdx.x * 32, k0 = blockIdx.y * 32;
  int tx = threadIdx.x, ty = threadIdx.y;  // (32,8)
#pragma unroll
  for (int r = 0; r < 4; ++r)
    t[ty + 8 * r][tx] = W[(size_t)(k0 + ty + 8 * r) * D + c0 + tx];
  __syncthreads();
#pragma unroll
  for (int r = 0; r < 4; ++r)
    Wt[(size_t)(blockIdx.z * D + c0 + ty + 8 * r) * K + k0 + tx] =
        __float2half(t[tx][ty + 8 * r]);
}

__global__ void bias4_kernel(const float* __restrict__ b0, const float* __restrict__ b1,
                             const float* __restrict__ b2, const float* __restrict__ b3,
                             float* __restrict__ bias_all, int D) {
  int c = blockIdx.x * 256 + threadIdx.x;
  if (c < 4 * D) {
    int m = c / D;
    const float* b = (m == 0) ? b0 : (m == 1) ? b1 : (m == 2) ? b2 : b3;
    bias_all[c] = b[c - m * D];
  }
}

// ---------------- MFMA GEMM: O[M x Ntot] = A[M x K] @ Wt^T + bias ----------------
__global__ __launch_bounds__(256)
void gemm_mfma_kernel(const __half* __restrict__ A, int lda,
                      const __half* __restrict__ Wt,
                      const float* __restrict__ bias,
                      __half* __restrict__ O, int Ntot, int K) {
  __shared__ __align__(16) __half As[128 * 32];
  __shared__ __align__(16) __half Bs[128 * 32];
  int tid = threadIdx.x;
  int wave = tid >> 6, lane = tid & 63;
  int wr = wave >> 1, wc = wave & 1;
  int m0 = blockIdx.x * 128;
  int n0 = blockIdx.y * 128;
  int lr = lane >> 2;
  int lk = (lane & 3) * 8;
  int quad = lane >> 4, rr = lane & 15;

  f32x4 acc[4][4] = {};

  for (int kt = 0; kt < K; kt += 32) {
#pragma unroll
    for (int p = 0; p < 2; ++p) {
      int chunk = p * 64 + wave * 16;
      const __half* ga = A + (size_t)(m0 + chunk + lr) * lda + kt + lk;
      load_lds16(ga, &As[chunk * 32]);
      const __half* gb = Wt + (size_t)(n0 + chunk + lr) * K + kt + lk;
      load_lds16(gb, &Bs[chunk * 32]);
    }
    __syncthreads();
    f16x8 a[4], b[4];
#pragma unroll
    for (int i = 0; i < 4; ++i)
      a[i] = *(const f16x8*)&As[(wr * 64 + i * 16 + rr) * 32 + quad * 8];
#pragma unroll
    for (int j = 0; j < 4; ++j)
      b[j] = *(const f16x8*)&Bs[(wc * 64 + j * 16 + rr) * 32 + quad * 8];
#pragma unroll
    for (int i = 0; i < 4; ++i)
#pragma unroll
      for (int j = 0; j < 4; ++j)
        acc[i][j] = __builtin_amdgcn_mfma_f32_16x16x32_f16(a[i], b[j], acc[i][j], 0, 0, 0);
    __syncthreads();
  }

  int col = lane & 15, rb = (lane >> 4) * 4;
  float bj[4];
#pragma unroll
  for (int j = 0; j < 4; ++j) bj[j] = bias[n0 + wc * 64 + j * 16 + col];
#pragma unroll
  for (int i = 0; i < 4; ++i) {
#pragma unroll
    for (int j = 0; j < 4; ++j) {
      int gc = n0 + wc * 64 + j * 16 + col;
#pragma unroll
      for (int r = 0; r < 4; ++r) {
        int gr = m0 + wr * 64 + i * 16 + rb + r;
        O[(size_t)gr * Ntot + gc] = __float2half(acc[i][j][r] + bj[j]);
      }
    }
  }
}

// ---------------- attention H=8 C=64: one WAVE per node ----------------
// lane owns channels [8*lane, 8*lane+8); head = lane>>3; 3-shfl reduce per head.
// QKVS row stride 2048 (cols: Q 0..511, K 512..1023, V 1024..1535, S 1536..2047).
// Writes relu(attn + S) into compact H[n*512 + ...], NT to avoid L3 pollution.
__global__ __launch_bounds__(256)
void attn_h8_kernel(const __half* __restrict__ QKVS,
                    const int* __restrict__ rowptr, const int* __restrict__ col,
                    __half* __restrict__ Hout, int N) {
  int n = blockIdx.x * 4 + (threadIdx.x >> 6);
  if (n >= N) return;
  int lane = threadIdx.x & 63;
  size_t rbase = (size_t)n * 2048 + lane * 8;

  f16x8 qv = __builtin_nontemporal_load((const f16x8*)(QKVS + rbase));
  float qf[8];
#pragma unroll
  for (int j = 0; j < 8; ++j) qf[j] = (float)qv[j];

  int e0 = rowptr[n], e1 = rowptr[n + 1];
  float m = -INFINITY, l = 0.f;
  float o[8] = {};
  for (int i = e0; i < e1; ++i) {
    int s = col[i];
    const __half* kvb = QKVS + (size_t)s * 2048 + 512 + lane * 8;
    f16x8 kv = *(const f16x8*)kvb;          // K row: 64 lanes x 16B = 1KB
    f16x8 vv = *(const f16x8*)(kvb + 512);  // V row
    float p = 0.f;
#pragma unroll
    for (int j = 0; j < 8; ++j) p += (float)kv[j] * qf[j];
    p += __shfl_xor(p, 1, 64);
    p += __shfl_xor(p, 2, 64);
    p += __shfl_xor(p, 4, 64);
    float a = p * 0.125f;  // 1/sqrt(64)
    float mn = fmaxf(m, a);
    float sc = __expf(m - mn);  // exp(-inf)=0 on first edge
    float e = __expf(a - mn);
    l = l * sc + e;
#pragma unroll
    for (int c = 0; c < 8; ++c) o[c] = o[c] * sc + e * (float)vv[c];
    m = mn;
  }
  float inv = 1.f / (l + 1e-16f);
  f16x8 sv = __builtin_nontemporal_load((const f16x8*)(QKVS + rbase + 1536));
  f16x8 hv;
#pragma unroll
  for (int c = 0; c < 8; ++c) {
    float r = o[c] * inv + (float)sv[c];
    hv[c] = (_Float16)fmaxf(r, 0.f);
  }
  __builtin_nontemporal_store(hv, (f16x8*)(Hout + (size_t)n * 512 + lane * 8));
}

// ---------------- attention H=1 C=64: 8-lane group per node, 8 nodes/wave ----------------
// QKVS2 row stride 256 (cols: Q 0..63, K 64..127, V 128..191, S 192..255). fp32 out.
__global__ __launch_bounds__(256)
void attn_h1_kernel(const __half* __restrict__ QKVS,
                    const int* __restrict__ rowptr, const int* __restrict__ col,
                    float* __restrict__ out, int N) {
  int n = (blockIdx.x * 256 + threadIdx.x) >> 3;
  if (n >= N) return;
  int gl = threadIdx.x & 7;
  size_t rbase = (size_t)n * 256 + gl * 8;

  f16x8 qv = __builtin_nontemporal_load((const f16x8*)(QKVS + rbase));
  float qf[8];
#pragma unroll
  for (int j = 0; j < 8; ++j) qf[j] = (float)qv[j];

  int e0 = rowptr[n], e1 = rowptr[n + 1];
  float m = -INFINITY, l = 0.f;
  float o[8] = {};
  for (int i = e0; i < e1; ++i) {
    int s = col[i];
    const __half* kvb = QKVS + (size_t)s * 256 + 64 + gl * 8;
    f16x8 kv = *(const f16x8*)kvb;
    f16x8 vv = *(const f16x8*)(kvb + 64);
    float p = 0.f;
#pragma unroll
    for (int j = 0; j < 8; ++j) p += (float)kv[j] * qf[j];
    p += __shfl_xor(p, 1, 64);
    p += __shfl_xor(p, 2, 64);
    p += __shfl_xor(p, 4, 64);
    float a = p * 0.125f;
    float mn = fmaxf(m, a);
    float sc = __expf(m - mn);
    float e = __expf(a - mn);
    l = l * sc + e;
#pragma unroll
    for (int c = 0; c < 8; ++c) o[c] = o[c] * sc + e * (float)vv[c];
    m = mn;
  }
  float inv = 1.f / (l + 1e-16f);
  f16x8 sv = __builtin_nontemporal_load((const f16x8*)(QKVS + rbase + 192));
  f32x4 r0, r1;
#pragma unroll
  for (int c = 0; c < 4; ++c) r0[c] = o[c] * inv + (float)sv[c];
#pragma unroll
  for (int c = 0; c < 4; ++c) r1[c] = o[c + 4] * inv + (float)sv[c + 4];
  float* op = out + (size_t)n * 64 + gl * 8;
  *(f32x4*)op = r0;
  *(f32x4*)(op + 4) = r1;
}

extern "C" void kernel_launch(void* const* d_in, const int* in_sizes, int n_in,
                              void* d_out, int out_size, void* d_ws, size_t ws_size,
                              hipStream_t stream) {
  const float* x = (const float*)d_in[0];
  const int* ei = (const int*)d_in[1];
  const int N = in_sizes[0] / 128;
  const int E = in_sizes[1] / 2;
  const int Npad = ((N + 127) / 128) * 128;
  const int* srcp = ei;
  const int* dstp = ei + E;

  const float* Wq0 = (const float*)d_in[2];  const float* bq0 = (const float*)d_in[3];
  const float* Wk0 = (const float*)d_in[4];  const float* bk0 = (const float*)d_in[5];
  const float* Wv0 = (const float*)d_in[6];  const float* bv0 = (const float*)d_in[7];
  const float* Ws0 = (const float*)d_in[8];  const float* bs0 = (const float*)d_in[9];
  const float* Wq1 = (const float*)d_in[10]; const float* bq1 = (const float*)d_in[11];
  const float* Wk1 = (const float*)d_in[12]; const float* bk1 = (const float*)d_in[13];
  const float* Wv1 = (const float*)d_in[14]; const float* bv1 = (const float*)d_in[15];
  const float* Ws1 = (const float*)d_in[16]; const float* bs1 = (const float*)d_in[17];
  const float* Wq2 = (const float*)d_in[18]; const float* bq2 = (const float*)d_in[19];
  const float* Wk2 = (const float*)d_in[20]; const float* bk2 = (const float*)d_in[21];
  const float* Wv2 = (const float*)d_in[22]; const float* bv2 = (const float*)d_in[23];
  const float* Ws2 = (const float*)d_in[24]; const float* bs2 = (const float*)d_in[25];

  // ---- workspace layout (~262.2 MB) ----
  char* p = (char*)d_ws;
  __half* O_all = (__half*)p;            p += (size_t)Npad * 2048 * 2;  // 205.0 MB
  __half* H     = (__half*)p;            p += (size_t)Npad * 512 * 2;   // 51.25 MB
  __half* X16   = H;  // aliases head of H; dead before H is first written
  __half* Wt    = (__half*)p;            p += (size_t)2048 * 512 * 2;   // 2 MB
  float* bias_all = (float*)p;           p += 2048 * 4;                 // 8 KB
  int* deg    = (int*)p;                 p += (size_t)N * 4;
  int* rowptr = (int*)p;                 p += (size_t)(N + 1) * 4;
  int* cursor = (int*)p;                 p += (size_t)(N + 1) * 4;
  int* colv   = (int*)p;                 p += (size_t)E * 4;
  size_t need = p - (char*)d_ws;
  if (ws_size < need) {
    fprintf(stderr, "kernel_launch: ws_size=%zu < need=%zu — aborting cleanly\n",
            ws_size, need);
    return;
  }

  // ---- prep ----
  convert_x_kernel<<<(Npad * 128 + 255) / 256, 256, 0, stream>>>(x, X16, N, Npad);
  zero_pad_kernel<<<((Npad - N) * 512 + 255) / 256, 256, 0, stream>>>(
      H, N * 512, (Npad - N) * 512);

  // ---- CSR build ----
  zero_int_kernel<<<(N + 255) / 256, 256, 0, stream>>>(deg, N);
  degree_kernel<<<(E + 255) / 256, 256, 0, stream>>>(dstp, deg, E);
  exscan_kernel<<<1, 1024, 0, stream>>>(deg, rowptr, cursor, N);
  scatter_kernel<<<(E + 255) / 256, 256, 0, stream>>>(srcp, dstp, cursor, colv, E);

  const int mtiles = Npad / 128;

  // ---- layer 0: K=128 -> Ntot=2048 ----
  transpose4_kernel<<<dim3(512 / 32, 128 / 32, 4), dim3(32, 8), 0, stream>>>(
      Wq0, Wk0, Wv0, Ws0, Wt, 128, 512);
  bias4_kernel<<<(2048 + 255) / 256, 256, 0, stream>>>(bq0, bk0, bv0, bs0, bias_all, 512);
  gemm_mfma_kernel<<<dim3(mtiles, 2048 / 128), 256, 0, stream>>>(
      X16, 128, Wt, bias_all, O_all, 2048, 128);
  attn_h8_kernel<<<(N + 3) / 4, 256, 0, stream>>>(O_all, rowptr, colv, H, N);

  // ---- layer 1: K=512 -> Ntot=2048 ----
  transpose4_kernel<<<dim3(512 / 32, 512 / 32, 4), dim3(32, 8), 0, stream>>>(
      Wq1, Wk1, Wv1, Ws1, Wt, 512, 512);
  bias4_kernel<<<(2048 + 255) / 256, 256, 0, stream>>>(bq1, bk1, bv1, bs1, bias_all, 512);
  gemm_mfma_kernel<<<dim3(mtiles, 2048 / 128), 256, 0, stream>>>(
      H, 512, Wt, bias_all, O_all, 2048, 512);
  attn_h8_kernel<<<(N + 3) / 4, 256, 0, stream>>>(O_all, rowptr, colv, H, N);

  // ---- layer 2: K=512 -> Ntot=256 (4 x 64) ----
  transpose4_kernel<<<dim3(64 / 32, 512 / 32, 4), dim3(32, 8), 0, stream>>>(
      Wq2, Wk2, Wv2, Ws2, Wt, 512, 64);
  bias4_kernel<<<1, 256, 0, stream>>>(bq2, bk2, bv2, bs2, bias_all, 64);
  gemm_mfma_kernel<<<dim3(mtiles, 256 / 128), 256, 0, stream>>>(
      H, 512, Wt, bias_all, O_all, 256, 512);
  attn_h1_kernel<<<(N + 31) / 32, 256, 0, stream>>>(O_all, rowptr, colv,
                                                    (float*)d_out, N);
}